// Round 2
// baseline (158.175 us; speedup 1.0000x reference)
//
#include <hip/hip_runtime.h>

#define NL2E (-1.4426950408889634f)

__device__ __forceinline__ float rl(float v, int lane) {
    return __int_as_float(__builtin_amdgcn_readlane(__float_as_int(v), lane));
}

__global__ __launch_bounds__(64) void leaf_integ_kernel(
    const float* __restrict__ S_conv, const float* __restrict__ up_mu_Z,
    const float* __restrict__ noise, const float* __restrict__ W_sub,
    const float* __restrict__ theta_syn, const float* __restrict__ theta_spike,
    const float* __restrict__ W_spike, const float* __restrict__ tau_hist,
    const float* __restrict__ K_hist, const float* __restrict__ delta_hist,
    float* __restrict__ out)
{
    const int SUB = 1024;
    int bid = blockIdx.x;
    // XCD-locality swizzle: consecutive s on same XCD so output lines merge in L2
    int s = ((bid & 7) << 7) + (bid >> 3);
    int l = threadIdx.x;

    __shared__ float lds_rev[128];

    // per-unit params (wave-uniform)
    float thsyn = theta_syn[s];
    float thspk = theta_spike[s];
    float wsub  = W_sub[s];
    float wspk  = W_spike[s];
    float delta = delta_hist[s];

    // history kernel for lag = lane, pre-scaled by -log2(e)
    float tt = fmaxf((float)l - delta, 0.0f);
    float kern = 0.0f;
    #pragma unroll
    for (int b = 0; b < 4; ++b) {
        float rtau = __expf(-tau_hist[b]);   // 1/exp(tau_hist[b])
        float ttau = tt * rtau;
        kern += ttau * __expf(-ttau) * K_hist[s * 4 + b];
    }
    float kvs = NL2E * kern;
    // lds_rev[a] = kern_scaled[(63 - a) & 63], doubled so per-phase read needs no mod
    lds_rev[63 - l]  = kvs;
    lds_rev[127 - l] = kvs;
    __syncthreads();

    // Preload rotated taps into registers: kreg[j] = scaled kern[(l-1-j)&63].
    // Eliminates the per-step ds_read + lgkm stall from the hot loop.
    float kreg[64];
    #pragma unroll
    for (int j = 0; j < 64; ++j) kreg[j] = lds_rev[64 - l + j];

    float thsynS = NL2E * thsyn;
    float c1 = NL2E * 0.5f * wspk;

    // prologue loads: block 0 (for A init + pre), block 1 s (reset source)
    float s0raw = S_conv[(size_t)l * SUB + s];
    float s1raw = S_conv[(size_t)(64 + l) * SUB + s];
    float up0   = up_mu_Z[(size_t)l * SUB + s];
    float n0    = noise[(size_t)l * SUB + s];

    // A: scaled accumulator; lane l holds next timestep t' == l (mod 64)
    float A    = fmaf(s0raw, NL2E, thsynS);
    float sA   = fmaf(s1raw, NL2E, thsynS);
    float preA = NL2E * (fmaf(0.5f, up0, 0.5f * thspk) + n0);
    float upA  = up0;

    // Software pipeline, depth 2: onep[j&1] = 1 + exp2(ab_j), prepared 2 phases early.
    float onep[2];
    onep[0] = 1.0f + __builtin_amdgcn_exp2f(rl(A, 0));
    onep[1] = 1.0f + __builtin_amdgcn_exp2f(rl(A, 1));
    float pbc = rl(preA, 0);

    float xcap = 0.0f, zcap = 0.0f;

    float* Yo = out;
    float* Zo = out + 4194304;
    float* Mo = out + 8388608;
    float* Do = out + 12582912;

    for (int m = 0; m < 64; ++m) {
        int t0 = m * 64;
        // prefetch next blocks (issue now, consumed at block end; clamped at tail)
        int tP = min(t0 + 128 + l, 4095);
        int tQ = min(t0 + 64 + l, 4095);
        float sB  = S_conv[(size_t)tP * SUB + s];
        float upB = up_mu_Z[(size_t)tQ * SUB + s];
        float nB  = noise[(size_t)tQ * SUB + s];

        #pragma unroll
        for (int j = 0; j < 64; ++j) {
            // phase j: sigmoid chain starts from pre-staged onep (ready 2 phases ago)
            float xo = __builtin_amdgcn_rcpf(onep[j & 1]);
            float vv = fmaf(xo, c1, pbc);
            float e2 = __builtin_amdgcn_exp2f(vv);
            float z  = __builtin_amdgcn_rcpf(1.0f + e2);

            bool sel = (l == j);
            xcap = sel ? xo : xcap;
            zcap = sel ? z  : zcap;
            float base = sel ? sA : A;               // lane j resets to s_{t+64}+theta
            A = fmaf(kreg[j], z, base);

            // prep phase j+2: lane (j+2)&63's A is final now
            // (phase j+1 contributes kern[0] == 0 to it)
            float ab2 = rl(A, (j + 2) & 63);
            onep[j & 1] = 1.0f + __builtin_amdgcn_exp2f(ab2);

            if (j < 63) pbc = rl(preA, j + 1);       // pb for phase j+1
        }

        // block-end: compute + store outputs vectorized (lane l holds phase l)
        float down = fmaf(xcap, wspk, thspk);
        float Yv   = xcap * wsub;
        float mu   = 0.5f * (upA + down);
        size_t o = (size_t)(t0 + l) * SUB + s;
        Yo[o] = Yv; Zo[o] = zcap; Mo[o] = mu; Do[o] = down;

        // swap double-buffered inputs
        sA   = fmaf(sB, NL2E, thsynS);
        preA = NL2E * (fmaf(0.5f, upB, 0.5f * thspk) + nB);
        upA  = upB;
        pbc  = rl(preA, 0);
    }
}

extern "C" void kernel_launch(void* const* d_in, const int* in_sizes, int n_in,
                              void* d_out, int out_size, void* d_ws, size_t ws_size,
                              hipStream_t stream) {
    const float* S_conv     = (const float*)d_in[0];
    const float* up_mu_Z    = (const float*)d_in[1];
    const float* noise      = (const float*)d_in[2];
    const float* W_sub      = (const float*)d_in[3];
    const float* theta_syn  = (const float*)d_in[4];
    const float* theta_spike= (const float*)d_in[5];
    const float* W_spike    = (const float*)d_in[6];
    const float* tau_hist   = (const float*)d_in[7];
    const float* K_hist     = (const float*)d_in[8];
    const float* delta_hist = (const float*)d_in[9];
    float* out = (float*)d_out;

    leaf_integ_kernel<<<dim3(1024), dim3(64), 0, stream>>>(
        S_conv, up_mu_Z, noise, W_sub, theta_syn, theta_spike, W_spike,
        tau_hist, K_hist, delta_hist, out);
}

// Round 3
// 130.401 us; speedup vs baseline: 1.2130x; 1.2130x over previous
//
#include <hip/hip_runtime.h>

#define NL2E (-1.4426950408889634f)

__device__ __forceinline__ float rl(float v, int lane) {
    return __int_as_float(__builtin_amdgcn_readlane(__float_as_int(v), lane));
}
__device__ __forceinline__ float bperm(int byteaddr, float v) {
    return __int_as_float(__builtin_amdgcn_ds_bpermute(byteaddr, __float_as_int(v)));
}

__global__ __launch_bounds__(64) void leaf_integ_kernel(
    const float* __restrict__ S_conv, const float* __restrict__ up_mu_Z,
    const float* __restrict__ noise, const float* __restrict__ W_sub,
    const float* __restrict__ theta_syn, const float* __restrict__ theta_spike,
    const float* __restrict__ W_spike, const float* __restrict__ tau_hist,
    const float* __restrict__ K_hist, const float* __restrict__ delta_hist,
    float* __restrict__ out)
{
    const int SUB = 1024;
    int bid = blockIdx.x;
    // XCD-locality swizzle: consecutive s on same XCD so output lines merge in L2
    int s = ((bid & 7) << 7) + (bid >> 3);
    int l = threadIdx.x;
    bool hi = (l >= 32);          // hi half-lanes process odd steps of each pair
    int pidx = hi ? 1 : 0;
    int rimR = l >> 1;            // iter at which this lane's accumulator resets
    int rimC = l & 31;            // iter at which this lane's half captures
    // block-end un-shuffle: lane l pulls from lane (l even ? l/2 : 32+l/2)
    int bpaddr = ((((l & 1) ? 32 : 0) + (l >> 1)) << 2);

    __shared__ float lds_rev[128];
    __shared__ float preLds[64];

    // per-unit params (wave-uniform)
    float thsyn = theta_syn[s];
    float thspk = theta_spike[s];
    float wsub  = W_sub[s];
    float wspk  = W_spike[s];
    float delta = delta_hist[s];

    // history kernel for lag = lane+1, pre-scaled by -log2(e)
    float tt = fmaxf((float)l - delta, 0.0f);
    float kern = 0.0f;
    #pragma unroll
    for (int b = 0; b < 4; ++b) {
        float rtau = __expf(-tau_hist[b]);
        float ttau = tt * rtau;
        kern += ttau * __expf(-ttau) * K_hist[s * 4 + b];
    }
    float kvs = NL2E * kern;
    lds_rev[63 - l]  = kvs;
    lds_rev[127 - l] = kvs;
    __syncthreads();

    // cross-pair correction constants (wave-uniform taps, packed per half):
    // kca multiplies z_{2i}:   lo(step 2i+2) needs kern[1], hi(step 2i+3) needs kern[2]
    // kcb multiplies z_{2i+1}: lo needs kern[0] (==0),      hi needs kern[1]
    float k0v = rl(kvs, 0);
    float k1v = rl(kvs, 1);
    float k2v = rl(kvs, 2);
    float kca = hi ? k2v : k1v;
    float kcb = hi ? k1v : k0v;

    const float* krow = &lds_rev[64 - l];  // krow[j] = scaled kern[(l-1-j)&63]

    float thsynS = NL2E * thsyn;
    float c1 = NL2E * 0.5f * wspk;

    // prologue loads
    float s0raw = S_conv[(size_t)l * SUB + s];
    float s1raw = S_conv[(size_t)(64 + l) * SUB + s];
    float up0   = up_mu_Z[(size_t)l * SUB + s];
    float n0    = noise[(size_t)l * SUB + s];

    float A    = fmaf(s0raw, NL2E, thsynS);   // lane l: accumulator for step == l (mod 64)
    float sA   = fmaf(s1raw, NL2E, thsynS);
    float preA = NL2E * (fmaf(0.5f, up0, 0.5f * thspk) + n0);
    float upA  = up0;

    // pipeline init: xoP = packed xo(steps 0,1); abN = packed ab(steps 2,3)
    // step 1's missing lag-1 tap has coefficient kern[0] == 0 -> exact.
    float ab01 = hi ? rl(A, 1) : rl(A, 0);
    float xoP  = __builtin_amdgcn_rcpf(1.0f + __builtin_amdgcn_exp2f(ab01));
    float abN  = hi ? rl(A, 3) : rl(A, 2);    // corrected during iter 0

    float* Yo = out;
    float* Zo = out + 4194304;
    float* Mo = out + 8388608;
    float* Do = out + 12582912;

    float xcapH = 0.0f, zcapH = 0.0f;
    float pbP = 0.0f;

    for (int B = 0; B < 64; ++B) {
        int t0 = B * 64;
        preLds[l] = preA;                      // this block's pb values
        pbP = hi ? rl(preA, 1) : rl(preA, 0);  // pb pair for steps 0,1

        // prefetch next blocks (consumed at block end; clamped at tail)
        int tP = min(t0 + 128 + l, 4095);
        int tQ = min(t0 + 64 + l, 4095);
        float sB  = S_conv[(size_t)tP * SUB + s];
        float upB = up_mu_Z[(size_t)tQ * SUB + s];
        float nB  = noise[(size_t)tQ * SUB + s];

        #pragma unroll
        for (int i = 0; i < 32; ++i) {
            float klo = krow[2 * i];           // taps for z_{2i} scatter
            float khi = krow[2 * i + 1];       // taps for z_{2i+1} scatter
            float pbN = (i < 31) ? preLds[2 * i + 2 + pidx] : 0.0f;

            // second sigmoid for the pair (z for steps 2i, 2i+1)
            float vv = fmaf(xoP, c1, pbP);
            float e2 = __builtin_amdgcn_exp2f(vv);
            float zP = __builtin_amdgcn_rcpf(1.0f + e2);

            // captures (per half); un-shuffled at block end
            bool cap = (rimC == i);
            xcapH = cap ? xoP : xcapH;
            zcapH = cap ? zP  : zcapH;

            float z0 = rl(zP, 0);              // z_{2i}
            float z1 = rl(zP, 32);             // z_{2i+1}

            // scatter into future accumulators; lanes 2i,2i+1 reset first
            float Ab = (rimR == i) ? sA : A;
            Ab = fmaf(klo, z0, Ab);
            A  = fmaf(khi, z1, Ab);

            // exact cross-pair corrections for steps 2i+2, 2i+3
            abN = fmaf(kca, z0, abN);
            abN = fmaf(kcb, z1, abN);

            // first sigmoid for next pair
            float e1 = __builtin_amdgcn_exp2f(abN);
            xoP = __builtin_amdgcn_rcpf(1.0f + e1);

            // pre-read ab for the pair after next (complete except this
            // correction mechanism's terms, applied next iter)
            float alo = rl(A, (2 * i + 4) & 63);
            float ahi = rl(A, (2 * i + 5) & 63);
            abN = hi ? ahi : alo;

            pbP = pbN;
        }

        // block end: un-shuffle captures so lane l holds step t0+l
        float xcap = bperm(bpaddr, xcapH);
        float zcap = bperm(bpaddr, zcapH);

        float down = fmaf(xcap, wspk, thspk);
        float Yv   = xcap * wsub;
        float mu   = 0.5f * (upA + down);
        size_t o = (size_t)(t0 + l) * SUB + s;
        Yo[o] = Yv; Zo[o] = zcap; Mo[o] = mu; Do[o] = down;

        // roll double-buffered inputs
        sA   = fmaf(sB, NL2E, thsynS);
        preA = NL2E * (fmaf(0.5f, upB, 0.5f * thspk) + nB);
        upA  = upB;
    }
}

extern "C" void kernel_launch(void* const* d_in, const int* in_sizes, int n_in,
                              void* d_out, int out_size, void* d_ws, size_t ws_size,
                              hipStream_t stream) {
    const float* S_conv     = (const float*)d_in[0];
    const float* up_mu_Z    = (const float*)d_in[1];
    const float* noise      = (const float*)d_in[2];
    const float* W_sub      = (const float*)d_in[3];
    const float* theta_syn  = (const float*)d_in[4];
    const float* theta_spike= (const float*)d_in[5];
    const float* W_spike    = (const float*)d_in[6];
    const float* tau_hist   = (const float*)d_in[7];
    const float* K_hist     = (const float*)d_in[8];
    const float* delta_hist = (const float*)d_in[9];
    float* out = (float*)d_out;

    leaf_integ_kernel<<<dim3(1024), dim3(64), 0, stream>>>(
        S_conv, up_mu_Z, noise, W_sub, theta_syn, theta_spike, W_spike,
        tau_hist, K_hist, delta_hist, out);
}